// Round 5
// baseline (317.810 us; speedup 1.0000x reference)
//
#include <hip/hip_runtime.h>

// InfoNCE fused pipeline (round 13):
//   cast   : W -> fp8 (scale 32). h cast is FUSED into g1f.
//   g1f    : Z' = h @ W8^T with in-kernel h fp32->fp8 conversion. Grid 256
//            (1 block/CU), block = 64 rows x 512 cols, wave owns 64x128
//            (acc[4][8]). r13: full dbuf As/Bs, ONE raw s_barrier per iter
//            with counted vmcnt(4) (T3/T4) -- Bs(k+1) async batch + h(k+2)
//            loads stay in flight across the barrier; staging issued after
//            the MFMA cluster into the non-read buffer (race-free: prior
//            readers of that buffer all passed the current barrier).
//            LDS traffic 49 KB/CU/iter (was 135 at the 16x512 wave shape).
//   g2_main: S = Z8F[:8192g] @ Z8F[8192g:]^T -- r11 design: wave owns
//            32 rows x 128 cols, A global once, B half-K LDS, 4 blocks/CU.
//   finalize: loss = mean(log(rowsumexp)) - mean(diag); sim_pos; sim_mean

typedef __attribute__((ext_vector_type(8))) short bf16x8;
typedef __attribute__((ext_vector_type(4))) float floatx4;  // MFMA C/D frag
typedef unsigned char uchar;

__device__ __forceinline__ unsigned short f2bf(float f) {
    union { float f; unsigned u; } v; v.f = f;
    unsigned r = (v.u + 0x7FFFu + ((v.u >> 16) & 1u)) >> 16;   // RNE
    return (unsigned short)r;
}

// async global->LDS, 16B per lane. LDS dest = wave-uniform base + lane*16.
__device__ __forceinline__ void async_copy16(const void* g, void* l) {
    __builtin_amdgcn_global_load_lds(
        (const __attribute__((address_space(1))) void*)g,
        (__attribute__((address_space(3))) void*)l,
        16, 0, 0);
}

// convert 16 fp32 (4 float4) -> 16 fp8 bytes, one b128 LDS write
__device__ __forceinline__ void cvt16(const float4* f, uchar* dst) {
    int4 pk;
    pk.x = (__builtin_amdgcn_cvt_pk_fp8_f32(f[0].x, f[0].y, 0, 0) & 0xffff)
         | (__builtin_amdgcn_cvt_pk_fp8_f32(f[0].z, f[0].w, 0, 0) << 16);
    pk.y = (__builtin_amdgcn_cvt_pk_fp8_f32(f[1].x, f[1].y, 0, 0) & 0xffff)
         | (__builtin_amdgcn_cvt_pk_fp8_f32(f[1].z, f[1].w, 0, 0) << 16);
    pk.z = (__builtin_amdgcn_cvt_pk_fp8_f32(f[2].x, f[2].y, 0, 0) & 0xffff)
         | (__builtin_amdgcn_cvt_pk_fp8_f32(f[2].z, f[2].w, 0, 0) << 16);
    pk.w = (__builtin_amdgcn_cvt_pk_fp8_f32(f[3].x, f[3].y, 0, 0) & 0xffff)
         | (__builtin_amdgcn_cvt_pk_fp8_f32(f[3].z, f[3].w, 0, 0) << 16);
    *reinterpret_cast<int4*>(dst) = pk;
}

// ---------------------------------------------------------------- cast fp32->fp8
__global__ __launch_bounds__(256) void cast_fp8_kernel(
    const float* __restrict__ src, uchar* __restrict__ dst, int n, float scale)
{
    const int i = (blockIdx.x * 256 + threadIdx.x) * 8;
    if (i + 7 < n) {
        float4 a = *reinterpret_cast<const float4*>(src + i);
        float4 b = *reinterpret_cast<const float4*>(src + i + 4);
        const int p01 = __builtin_amdgcn_cvt_pk_fp8_f32(a.x * scale, a.y * scale, 0, 0);
        const int p23 = __builtin_amdgcn_cvt_pk_fp8_f32(a.z * scale, a.w * scale, 0, 0);
        const int p45 = __builtin_amdgcn_cvt_pk_fp8_f32(b.x * scale, b.y * scale, 0, 0);
        const int p67 = __builtin_amdgcn_cvt_pk_fp8_f32(b.z * scale, b.w * scale, 0, 0);
        int2 w;
        w.x = (p01 & 0xffff) | (p23 << 16);
        w.y = (p45 & 0xffff) | (p67 << 16);
        *reinterpret_cast<int2*>(dst + i) = w;
    }
}

// store helper: fp8 byte for (row_g, col_g) into frag-layout Z8F
__device__ __forceinline__ size_t fl_off(int row_g, int col_g) {
    const int g = row_g >> 4, r15 = row_g & 15;
    const int c = col_g >> 5, q = (col_g >> 3) & 3, b = col_g & 7;
    return ((size_t)g * 16 + c) * 512 + (size_t)(q * 16 + r15) * 8 + b;
}

// ---------------------------------------------------------------- g1f (fused cast + GEMM)
// Body macro: K = k-iter; FC = f-regs holding h(K+1) (consumed -> As[nbuf]);
// FN = f-regs to receive h(K+2); AR/BR = read buffers (chunk K);
// AW/BW = write buffers (chunk K+1); VM = vmcnt immediate at entry.
#define G1F_BODY(K, FC, FN, AR, BR, AW, BW, VM, STAGE_B, STAGE_H)              \
  {                                                                            \
    asm volatile("s_waitcnt vmcnt(" #VM ")" ::: "memory");                     \
    asm volatile("s_waitcnt lgkmcnt(0)" ::: "memory");                         \
    __builtin_amdgcn_s_barrier();                                              \
    __builtin_amdgcn_sched_barrier(0);                                         \
    long av[2][4], bv[2][8];                                                   \
    _Pragma("unroll")                                                          \
    for (int c = 0; c < 2; c++) {                                              \
      _Pragma("unroll")                                                        \
      for (int i = 0; i < 4; i++)                                              \
        av[c][i] = *reinterpret_cast<const long*>(AR + fA + i * 1024 + c * 32);\
      _Pragma("unroll")                                                        \
      for (int j = 0; j < 8; j++)                                              \
        bv[c][j] = *reinterpret_cast<const long*>(BR + fB + j * 1024 + c * 32);\
    }                                                                          \
    __builtin_amdgcn_s_setprio(1);                                             \
    _Pragma("unroll")                                                          \
    for (int c = 0; c < 2; c++)                                                \
      _Pragma("unroll")                                                        \
      for (int i = 0; i < 4; i++)                                              \
        _Pragma("unroll")                                                      \
        for (int j = 0; j < 8; j++)                                            \
          acc[i][j] = __builtin_amdgcn_mfma_f32_16x16x32_fp8_fp8(              \
              av[c][i], bv[c][j], acc[i][j], 0, 0, 0);                         \
    __builtin_amdgcn_s_setprio(0);                                             \
    if (STAGE_B) {                                                             \
      _Pragma("unroll")                                                        \
      for (int s = 0; s < 8; s++)                                              \
        async_copy16(gBs + ((K) + 1) * 64 + s * 131072, BW + swave + s * 4096);\
      cvt16(FC, AW + aoff);                                                    \
    }                                                                          \
    if (STAGE_H) {                                                             \
      _Pragma("unroll")                                                        \
      for (int c4 = 0; c4 < 4; c4++)                                           \
        FN[c4] = *reinterpret_cast<const float4*>(gH + ((K) + 2) * 64 + c4 * 4);\
    }                                                                          \
  }

__global__ __launch_bounds__(256, 1) void g1f(
    const float* __restrict__ h, const uchar* __restrict__ W8,
    uchar* __restrict__ Z8F, float* __restrict__ norm2)
{
    __shared__ __align__(16) uchar As0[64 * 64],  As1[64 * 64];    // 2 x 4 KB
    __shared__ __align__(16) uchar Bs0[512 * 64], Bs1[512 * 64];   // 2 x 32 KB

    const int blk = blockIdx.x;         // rows [blk*64, +64)
    const int t = threadIdx.x;
    const int wave = t >> 6, lane = t & 63;
    const int quad = lane >> 4, l15 = lane & 15;

    floatx4 acc[4][8];
    #pragma unroll
    for (int i = 0; i < 4; i++)
        #pragma unroll
        for (int j = 0; j < 8; j++) acc[i][j] = {0.f, 0.f, 0.f, 0.f};

    // As producer: thread t owns (row t>>2, float-slot t&3): 16 floats/iter
    const int arow = t >> 2, ap = t & 3;
    const float* gH = h + (size_t)(blk * 64 + arow) * 2048 + ap * 16;
    const int aoff = arow * 64 + ap * 16;                     // linear As dest

    // Bs staging: wave w, stage s covers W8 rows [s*64 + w*16, +16).
    // Source per-lane; dest wave-uniform (HW adds lane*16) -> linear [row][64].
    const uchar* gBs = W8 + (size_t)(wave * 16 + (lane >> 2)) * 2048 + (lane & 3) * 16;
    const int swave = wave * 1024;

    // frag read offsets (linear layout: row*64 + quad*8, +c*32 for K-halves)
    const int fA = l15 * 64 + quad * 8;
    const int fB = wave * 8192 + l15 * 64 + quad * 8;         // wave's 8 col-tiles

    // ---- prologue: Bs(0)->Bs0, h(0)->p0, h(1)->f1, As(0)<-p0
    #pragma unroll
    for (int s = 0; s < 8; s++)
        async_copy16(gBs + s * 131072, Bs0 + swave + s * 4096);
    float4 p0[4], f0[4], f1[4];
    #pragma unroll
    for (int c = 0; c < 4; c++) p0[c] = *reinterpret_cast<const float4*>(gH + c * 4);
    #pragma unroll
    for (int c = 0; c < 4; c++) f1[c] = *reinterpret_cast<const float4*>(gH + 64 + c * 4);
    cvt16(p0, As0 + aoff);

    // ---- main loop: 32 K-iters, 2 per trip (static buffer roles)
    for (int kb = 0; kb < 15; kb++) {
        const int k = kb * 2;
        G1F_BODY(k,     f1, f0, As0, Bs0, As1, Bs1, 4, 1, 1)
        G1F_BODY(k + 1, f0, f1, As1, Bs1, As0, Bs0, 4, 1, 1)
    }
    G1F_BODY(30, f1, f0, As0, Bs0, As1, Bs1, 4, 1, 0)   // stage Bs(31)/As(31), no h
    G1F_BODY(31, f0, f1, As1, Bs1, As0, Bs0, 0, 0, 0)   // drain all, no staging

    // ---- epilogue: quantize, frag-layout store, norm2 partial via atomic
    #pragma unroll
    for (int i = 0; i < 4; i++) {
        #pragma unroll
        for (int r = 0; r < 4; r++) {
            const int row_g = blk * 64 + i * 16 + quad * 4 + r;
            float pw = 0.f;
            #pragma unroll
            for (int jp = 0; jp < 4; jp++) {
                const int pk = __builtin_amdgcn_cvt_pk_fp8_f32(
                    acc[i][2 * jp][r], acc[i][2 * jp + 1][r], 0, 0);
                Z8F[fl_off(row_g, wave * 128 + (2 * jp) * 16 + l15)]     = (uchar)(pk & 0xff);
                Z8F[fl_off(row_g, wave * 128 + (2 * jp + 1) * 16 + l15)] = (uchar)((pk >> 8) & 0xff);
                const float q0 = __builtin_amdgcn_cvt_f32_fp8(pk, 0);
                const float q1 = __builtin_amdgcn_cvt_f32_fp8(pk, 1);
                pw += q0 * q0 + q1 * q1;
            }
            pw += __shfl_xor(pw, 1, 16);
            pw += __shfl_xor(pw, 2, 16);
            pw += __shfl_xor(pw, 4, 16);
            pw += __shfl_xor(pw, 8, 16);
            if (l15 == 0) atomicAdd(&norm2[row_g], pw);
        }
    }
}

// ---------------------------------------------------------------- g1_slow (fallback, fp32 in)
__global__ __launch_bounds__(256) void g1_slow(
    const float* __restrict__ h, const float* __restrict__ W,
    uchar* __restrict__ Z8F, float* __restrict__ norm2)
{
    __shared__ __align__(16) unsigned short As[128][40];
    __shared__ __align__(16) unsigned short Bs[128][40];

    const int bn = blockIdx.x, bm = blockIdx.y;
    const int t = threadIdx.x;
    const int wave = t >> 6, lane = t & 63;
    const int wm = wave & 1, wn = wave >> 1;
    const int quad = lane >> 4, l15 = lane & 15;

    floatx4 acc[4][4];
    #pragma unroll
    for (int i = 0; i < 4; i++)
        #pragma unroll
        for (int j = 0; j < 4; j++) acc[i][j] = {0.f, 0.f, 0.f, 0.f};

    const int lrow = t >> 1, lhalf = t & 1;
    const float* ga = h + (size_t)(bm * 128 + lrow) * 2048 + lhalf * 16;
    const float* gb = W + (size_t)(bn * 128 + lrow) * 2048 + lhalf * 16;

    for (int k0 = 0; k0 < 2048; k0 += 32) {
        #pragma unroll
        for (int c = 0; c < 4; c++) {
            const float4 va = *reinterpret_cast<const float4*>(ga + k0 + c * 4);
            const float4 vb = *reinterpret_cast<const float4*>(gb + k0 + c * 4);
            ushort4 ua = make_ushort4(f2bf(va.x), f2bf(va.y), f2bf(va.z), f2bf(va.w));
            ushort4 ub = make_ushort4(f2bf(vb.x), f2bf(vb.y), f2bf(vb.z), f2bf(vb.w));
            *reinterpret_cast<ushort4*>(&As[lrow][lhalf * 16 + c * 4]) = ua;
            *reinterpret_cast<ushort4*>(&Bs[lrow][lhalf * 16 + c * 4]) = ub;
        }
        __syncthreads();
        bf16x8 af[4], bfr[4];
        #pragma unroll
        for (int i = 0; i < 4; i++)
            af[i] = *reinterpret_cast<const bf16x8*>(&As[wm * 64 + i * 16 + l15][quad * 8]);
        #pragma unroll
        for (int j = 0; j < 4; j++)
            bfr[j] = *reinterpret_cast<const bf16x8*>(&Bs[wn * 64 + j * 16 + l15][quad * 8]);
        #pragma unroll
        for (int i = 0; i < 4; i++)
            #pragma unroll
            for (int j = 0; j < 4; j++)
                acc[i][j] = __builtin_amdgcn_mfma_f32_16x16x32_bf16(af[i], bfr[j], acc[i][j], 0, 0, 0);
        __syncthreads();
    }

    #pragma unroll
    for (int i = 0; i < 4; i++) {
        #pragma unroll
        for (int r = 0; r < 4; r++) {
            const int row_g = bm * 128 + wm * 64 + i * 16 + quad * 4 + r;
            const int pk01 = __builtin_amdgcn_cvt_pk_fp8_f32(acc[i][0][r], acc[i][1][r], 0, 0);
            const int pk23 = __builtin_amdgcn_cvt_pk_fp8_f32(acc[i][2][r], acc[i][3][r], 0, 0);
            const uchar q8[4] = { (uchar)(pk01 & 0xff), (uchar)((pk01 >> 8) & 0xff),
                                  (uchar)(pk23 & 0xff), (uchar)((pk23 >> 8) & 0xff) };
            #pragma unroll
            for (int j = 0; j < 4; j++) {
                const int col_g = bn * 128 + wn * 64 + j * 16 + l15;
                Z8F[fl_off(row_g, col_g)] = q8[j];
            }
            const float q0 = __builtin_amdgcn_cvt_f32_fp8(pk01, 0);
            const float q1 = __builtin_amdgcn_cvt_f32_fp8(pk01, 1);
            const float q2 = __builtin_amdgcn_cvt_f32_fp8(pk23, 0);
            const float q3 = __builtin_amdgcn_cvt_f32_fp8(pk23, 1);
            float pw = q0 * q0 + q1 * q1 + q2 * q2 + q3 * q3;
            pw += __shfl_xor(pw, 1, 16);
            pw += __shfl_xor(pw, 2, 16);
            pw += __shfl_xor(pw, 4, 16);
            pw += __shfl_xor(pw, 8, 16);
            if (l15 == 0) atomicAdd(&norm2[row_g], pw);
        }
    }
}

// ---------------------------------------------------------------- g2_main
// S = Z8F[:8192g] @ Z8F[8192g:]^T, fp8 16x16x32 MFMA, 128x128 tile.
// r11: wave w owns rows [w*32,+32) x 128 cols; A global (read once/block),
// B half-K (32 KB) in LDS, restaged mid-loop. 4 blocks/CU -> 4 waves/SIMD.
__global__ __launch_bounds__(256, 4) void g2_main(
    const uchar* __restrict__ Z8F, const float* __restrict__ norm2,
    float* __restrict__ rowse, float* __restrict__ bsum, float* __restrict__ bdiag)
{
    __shared__ __align__(16) uchar Bs[32768];      // half-K B tile (32 KB)
    __shared__ float red[8];
    float (*lds_red)[20] = (float (*)[20])(void*)Bs;  // post-loop overlay [128][20]

    // XCD-aware remap: 4096 blocks, o%8 = XCD, 512 blocks/XCD.
    const int o = blockIdx.y * 64 + blockIdx.x;
    const int xcd = o & 7, idx = o >> 3;           // idx in [0,512)
    const int bg = idx >> 7, r = idx & 127;        // bn-group, inner
    const int bm = xcd * 8 + (r >> 4);             // 0..63
    const int bn = bg * 16 + (r & 15);             // 0..63
    const int t = threadIdx.x;
    const int wave = t >> 6, lane = t & 63;
    const int quad = lane >> 4, l15 = lane & 15;

    // B tile = Z rows [8192 + bn*128, +128) x K=512 B, frag layout: 8 groups
    // of 8 KB; half h = bytes [h*4096, +4096) of each group (c in [h*8,+8)).
    const uchar* gB = Z8F + (size_t)(512 + bn * 8) * 8192 + t * 16;
    #pragma unroll
    for (int s = 0; s < 8; s++)                     // stage half 0
        async_copy16(gB + s * 8192, &Bs[s * 4096 + wave * 1024]);

    floatx4 acc[2][8];
    #pragma unroll
    for (int i = 0; i < 2; i++)
        #pragma unroll
        for (int j = 0; j < 8; j++) acc[i][j] = {0.f, 0.f, 0.f, 0.f};

    // A: wave w owns row groups bm*8 + w*2 + i (i=0,1), all 16 c-steps.
    const uchar* baseA = Z8F + (size_t)(bm * 8 + wave * 2) * 8192 + lane * 8;

    // distance-2 A ring (cheap even if the scheduler re-sinks it; TLP is
    // the primary latency cover at 4 waves/SIMD)
    long ab[3][2];
    #pragma unroll
    for (int d = 0; d < 2; d++)
        #pragma unroll
        for (int i = 0; i < 2; i++)
            ab[d][i] = *reinterpret_cast<const long*>(baseA + i * 8192 + d * 512);

    __syncthreads();   // half 0 staged & visible

    #pragma unroll
    for (int c = 0; c < 16; c++) {
        const int cl = c & 7;
        if (c < 14) {
            #pragma unroll
            for (int i = 0; i < 2; i++)
                ab[(c + 2) % 3][i] = *reinterpret_cast<const long*>(
                    baseA + i * 8192 + (c + 2) * 512);
        }
        long bb[8];
        #pragma unroll
        for (int j = 0; j < 8; j++)
            bb[j] = *reinterpret_cast<const long*>(&Bs[j * 4096 + cl * 512 + lane * 8]);
        __builtin_amdgcn_s_setprio(1);
        #pragma unroll
        for (int i = 0; i < 2; i++)
            #pragma unroll
            for (int j = 0; j < 8; j++)
                acc[i][j] = __builtin_amdgcn_mfma_f32_16x16x32_fp8_fp8(
                    ab[c % 3][i], bb[j], acc[i][j], 0, 0, 0);
        __builtin_amdgcn_s_setprio(0);
        if (c == 7) {
            __syncthreads();                        // all waves done with half 0
            #pragma unroll
            for (int s = 0; s < 8; s++)             // stage half 1
                async_copy16(gB + s * 8192 + 4096, &Bs[s * 4096 + wave * 1024]);
            __syncthreads();                        // drained & visible
        }
    }

    __syncthreads();   // all waves done reading Bs before lds_red overlay

    // Slim epilogue: sim2 = dot * rz * rc * (10*log2e); rowexp via exp2.
    float rc8[8];
    #pragma unroll
    for (int j = 0; j < 8; j++)
        rc8[j] = rsqrtf(fmaxf(norm2[8192 + bn * 128 + j * 16 + l15], 1e-30f));

    const bool diagblk = (bm == bn);
    float s_tot2 = 0.f, s_diag2 = 0.f;
    #pragma unroll
    for (int i = 0; i < 2; i++) {
        #pragma unroll
        for (int rr = 0; rr < 4; rr++) {
            const int row_t = wave * 32 + i * 16 + quad * 4 + rr;
            const float rzl2 = rsqrtf(fmaxf(norm2[bm * 128 + row_t], 1e-30f)) * 14.4269504089f;
            float rx = 0.f;
            #pragma unroll
            for (int j = 0; j < 8; j++) {
                const float sim2 = acc[i][j][rr] * rzl2 * rc8[j];
                s_tot2 += sim2;
                rx += exp2f(sim2);
                if (diagblk && j == wave * 2 + i && l15 == quad * 4 + rr)
                    s_diag2 += sim2;
            }
            lds_red[row_t][l15] = rx;   // row stride 20: quads 2-way = free
        }
    }
    __syncthreads();

    // batched row reduction: 256 threads -> 128 rows x 2 col-half partials
    {
        const int row = t >> 1, half = t & 1;
        float v = 0.f;
        #pragma unroll
        for (int cc = 0; cc < 8; cc++) v += lds_red[row][half * 8 + cc];
        v += __shfl_xor(v, 1, 64);          // combine the two col-halves
        if (half == 0) atomicAdd(&rowse[bm * 128 + row], v);
    }

    #pragma unroll
    for (int off = 32; off; off >>= 1) {
        s_tot2  += __shfl_xor(s_tot2, off, 64);
        s_diag2 += __shfl_xor(s_diag2, off, 64);
    }
    if (lane == 0) { red[wave] = s_tot2; red[4 + wave] = s_diag2; }
    __syncthreads();
    if (t == 0) {
        bsum[bm * 64 + bn]  = (red[0] + red[1] + red[2] + red[3]) * 0.69314718056f;
        bdiag[bm * 64 + bn] = (red[4] + red[5] + red[6] + red[7]) * 0.69314718056f;
    }
}

// ---------------------------------------------------------------- finalize
__global__ __launch_bounds__(256) void finalize_kernel(
    const float* __restrict__ rowse, const float* __restrict__ bsum,
    const float* __restrict__ bdiag, float* __restrict__ out)
{
    float a = 0.f, b = 0.f, c = 0.f;
    for (int i = threadIdx.x; i < 8192; i += 256) a += logf(rowse[i]);
    for (int i = threadIdx.x; i < 4096; i += 256) { b += bsum[i]; c += bdiag[i]; }
    #pragma unroll
    for (int off = 32; off; off >>= 1) {
        a += __shfl_xor(a, off, 64);
        b += __shfl_xor(b, off, 64);
        c += __shfl_xor(c, off, 64);
    }
    __shared__ float ra[4], rb[4], rc[4];
    const int wave = threadIdx.x >> 6, lane = threadIdx.x & 63;
    if (lane == 0) { ra[wave] = a; rb[wave] = b; rc[wave] = c; }
    __syncthreads();
    if (threadIdx.x == 0) {
        const float A = ra[0] + ra[1] + ra[2] + ra[3];
        const float B = rb[0] + rb[1] + rb[2] + rb[3];
        const float C = rc[0] + rc[1] + rc[2] + rc[3];
        const float diag_mean = C / 8192.f;
        out[0] = A / 8192.f - diag_mean;            // loss
        out[1] = diag_mean;                         // sim_pos
        out[2] = B / (8192.f * 8192.f);             // sim_mean
    }
}

// ---------------------------------------------------------------- launch
extern "C" void kernel_launch(void* const* d_in, const int* in_sizes, int n_in,
                              void* d_out, int out_size, void* d_ws, size_t ws_size,
                              hipStream_t stream) {
    const float* h = (const float*)d_in[0];   // [16384, 2048]
    const float* W = (const float*)d_in[1];   // [512, 2048]
    float* out = (float*)d_out;               // [3]

    char* ws = (char*)d_ws;
    float* norm2 = (float*)(ws);                            // 16384 f @ 0
    float* rowse = (float*)(ws + 65536);                    //  8192 f
    float* bsum  = (float*)(ws + 98304);                    //  4096 f
    float* bdiag = (float*)(ws + 114688);                   //  4096 f
    uchar* Z8F   = (uchar*)(ws + 131072);                   // frag-layout fp8 (8.39 MB)
    uchar* W8    = (uchar*)(ws + 8519680);                  // 512x2048 fp8 (1 MB)
    const size_t NEED_FAST = 9568256ull;                    // ~9.6 MB

    hipMemsetAsync(ws, 0, 131072, stream);    // zero norm2 + rowse (+bsum/bdiag)

    if (ws_size >= NEED_FAST) {
        const int nw = 512 * 2048;
        hipLaunchKernelGGL(cast_fp8_kernel, dim3(nw / 2048), dim3(256), 0, stream, W, W8, nw, 32.0f);
        hipLaunchKernelGGL(g1f, dim3(256), dim3(256), 0, stream, h, W8, Z8F, norm2);
    } else {
        hipLaunchKernelGGL(g1_slow, dim3(4, 128), dim3(256), 0, stream, h, W, Z8F, norm2);
    }
    hipLaunchKernelGGL(g2_main, dim3(64, 64), dim3(256), 0, stream, Z8F, norm2, rowse, bsum, bdiag);
    hipLaunchKernelGGL(finalize_kernel, dim3(1), dim3(256), 0, stream, rowse, bsum, bdiag, out);
}

// Round 6
// 284.697 us; speedup vs baseline: 1.1163x; 1.1163x over previous
//
#include <hip/hip_runtime.h>

// InfoNCE fused pipeline (round 14):
//   cast_w_frag: W -> fp8 (scale 32) stored directly in MFMA FRAG layout
//            (W8F), so g1r's B-fragment loads are contiguous 512B blocks.
//   g1r    : Z' = h @ W8F^T with in-kernel h fp32->fp8 conversion.
//            Grid 256 x 512 threads (8 waves = 2/SIMD), M=64, wave owns
//            64x64 (acc[4][4]). KEY (r14): B frags load DIRECT from W8F
//            (L2-resident, zero inter-wave reuse -> LDS staging of B was
//            pure overhead); LDS only for the 4KB A exchange (dbuf, ONE
//            barrier/iter, r12-proven XOR slot swizzle). h read once.
//   g2_main: S = Z8F[:8192g] @ Z8F[8192g:]^T -- r11 design: wave owns
//            32 rows x 128 cols, A global once, B half-K LDS, 4 blocks/CU.
//   finalize: loss = mean(log(rowsumexp)) - mean(diag); sim_pos; sim_mean

typedef __attribute__((ext_vector_type(8))) short bf16x8;
typedef __attribute__((ext_vector_type(4))) float floatx4;  // MFMA C/D frag
typedef unsigned char uchar;

__device__ __forceinline__ unsigned short f2bf(float f) {
    union { float f; unsigned u; } v; v.f = f;
    unsigned r = (v.u + 0x7FFFu + ((v.u >> 16) & 1u)) >> 16;   // RNE
    return (unsigned short)r;
}

// async global->LDS, 16B per lane. LDS dest = wave-uniform base + lane*16.
__device__ __forceinline__ void async_copy16(const void* g, void* l) {
    __builtin_amdgcn_global_load_lds(
        (const __attribute__((address_space(1))) void*)g,
        (__attribute__((address_space(3))) void*)l,
        16, 0, 0);
}

// convert 8 fp32 (2 float4) -> 8 fp8 bytes (one b64 LDS write)
__device__ __forceinline__ void cvt8(const float4* f, uchar* dst) {
    int2 pk;
    pk.x = (__builtin_amdgcn_cvt_pk_fp8_f32(f[0].x, f[0].y, 0, 0) & 0xffff)
         | (__builtin_amdgcn_cvt_pk_fp8_f32(f[0].z, f[0].w, 0, 0) << 16);
    pk.y = (__builtin_amdgcn_cvt_pk_fp8_f32(f[1].x, f[1].y, 0, 0) & 0xffff)
         | (__builtin_amdgcn_cvt_pk_fp8_f32(f[1].z, f[1].w, 0, 0) << 16);
    *reinterpret_cast<int2*>(dst) = pk;
}

// store helper: fp8 byte for (row_g, col_g) into frag-layout Z8F
__device__ __forceinline__ size_t fl_off(int row_g, int col_g) {
    const int g = row_g >> 4, r15 = row_g & 15;
    const int c = col_g >> 5, q = (col_g >> 3) & 3, b = col_g & 7;
    return ((size_t)g * 16 + c) * 512 + (size_t)(q * 16 + r15) * 8 + b;
}

// ---------------------------------------------------------------- cast W -> frag-layout fp8
// W8F byte for W row r, K-byte k: tile g=r>>4, chunk c=k>>5, quad q=(k>>3)&3:
//   off = g*32768 + c*512 + q*128 + (r&15)*8 + (k&7)
// so a B-frag load (g, c) is 512B contiguous: lane (q*16+r15) reads +lane*8.
__global__ __launch_bounds__(256) void cast_w_frag(
    const float* __restrict__ W, uchar* __restrict__ W8F)
{
    const int i = (blockIdx.x * 256 + threadIdx.x) * 8;   // 8 consecutive k, same row
    const int r = i >> 11, k = i & 2047;
    const float* s = W + (size_t)r * 2048 + k;
    float4 a = *reinterpret_cast<const float4*>(s);
    float4 b = *reinterpret_cast<const float4*>(s + 4);
    int2 w;
    w.x = (__builtin_amdgcn_cvt_pk_fp8_f32(a.x * 32.f, a.y * 32.f, 0, 0) & 0xffff)
        | (__builtin_amdgcn_cvt_pk_fp8_f32(a.z * 32.f, a.w * 32.f, 0, 0) << 16);
    w.y = (__builtin_amdgcn_cvt_pk_fp8_f32(b.x * 32.f, b.y * 32.f, 0, 0) & 0xffff)
        | (__builtin_amdgcn_cvt_pk_fp8_f32(b.z * 32.f, b.w * 32.f, 0, 0) << 16);
    const size_t off = (size_t)(r >> 4) * 32768 + (size_t)(k >> 5) * 512
                     + (size_t)((k >> 3) & 3) * 128 + (size_t)(r & 15) * 8;
    *reinterpret_cast<int2*>(W8F + off) = w;
}

// ---------------------------------------------------------------- g1r (fused cast + GEMM)
// One iter: barrier; A-frags from AsR (XOR-swizzled b64); B-frags direct
// from W8F (8 x global b64, contiguous 512B blocks); stage h chunk K+1 into
// AsW (cvt8 + ds_write, other buffer -> race-free); load h chunk K+2; MFMA.
#define G1R_ITER(K, AsR, AsW, FC, FN, DO_CVT, DO_LOAD)                         \
  {                                                                            \
    __syncthreads();                                                           \
    long av[4][2];                                                             \
    _Pragma("unroll")                                                          \
    for (int i = 0; i < 4; i++)                                                \
      _Pragma("unroll")                                                        \
      for (int c = 0; c < 2; c++)                                              \
        av[i][c] = *reinterpret_cast<const long*>(                             \
            AsR + (i * 16 + l15) * 64 +                                        \
            (((c * 2 + (quad >> 1)) ^ (l15 & 3)) << 4) + (quad & 1) * 8);      \
    long bb[4][2];                                                             \
    _Pragma("unroll")                                                          \
    for (int j = 0; j < 4; j++)                                                \
      _Pragma("unroll")                                                        \
      for (int c = 0; c < 2; c++)                                              \
        bb[j][c] = *reinterpret_cast<const long*>(                             \
            gWF + j * 32768 + ((K) * 2 + c) * 512);                            \
    if (DO_CVT) cvt8(FC, AsW + adst);                                          \
    if (DO_LOAD) {                                                             \
      FN[0] = *reinterpret_cast<const float4*>(gH + ((K) + 2) * 64);           \
      FN[1] = *reinterpret_cast<const float4*>(gH + ((K) + 2) * 64 + 4);       \
    }                                                                          \
    __builtin_amdgcn_s_setprio(1);                                             \
    _Pragma("unroll")                                                          \
    for (int c = 0; c < 2; c++)                                                \
      _Pragma("unroll")                                                        \
      for (int i = 0; i < 4; i++)                                              \
        _Pragma("unroll")                                                      \
        for (int j = 0; j < 4; j++)                                            \
          acc[i][j] = __builtin_amdgcn_mfma_f32_16x16x32_fp8_fp8(              \
              av[i][c], bb[j][c], acc[i][j], 0, 0, 0);                         \
    __builtin_amdgcn_s_setprio(0);                                             \
  }

__global__ __launch_bounds__(512, 2) void g1r(
    const float* __restrict__ h, const uchar* __restrict__ W8F,
    uchar* __restrict__ Z8F, float* __restrict__ norm2)
{
    __shared__ __align__(16) uchar As0[64 * 64], As1[64 * 64];   // 2 x 4 KB

    const int blk = blockIdx.x;          // rows [blk*64, +64)
    const int t = threadIdx.x;
    const int wave = t >> 6, lane = t & 63;
    const int quad = lane >> 4, l15 = lane & 15;

    floatx4 acc[4][4];
    #pragma unroll
    for (int i = 0; i < 4; i++)
        #pragma unroll
        for (int j = 0; j < 4; j++) acc[i][j] = {0.f, 0.f, 0.f, 0.f};

    // h producer: thread t owns (row = t>>3, 8-byte unit u = t&7) of each
    // 64-float K-chunk. Write to As with the r12-proven XOR slot swizzle:
    // logical 16B-slot s = u>>1 -> phys slot s ^ (row&3).
    const int arow = t >> 3, u = t & 7;
    const float* gH = h + (size_t)(blk * 64 + arow) * 2048 + u * 8;
    const int adst = arow * 64 + (((u >> 1) ^ (arow & 3)) << 4) + (u & 1) * 8;

    // B: wave owns col-tiles [wave*4, +4); frag (tile j, chunk c) at
    // gWF + j*32768 + c*512 (+lane*8 folded into gWF).
    const uchar* gWF = W8F + (size_t)(wave * 4) * 32768 + lane * 8;

    // prologue: chunk 0 -> f0 -> As0; chunk 1 -> f1
    float4 f0[2], f1[2];
    f0[0] = *reinterpret_cast<const float4*>(gH);
    f0[1] = *reinterpret_cast<const float4*>(gH + 4);
    cvt8(f0, As0 + adst);
    f1[0] = *reinterpret_cast<const float4*>(gH + 64);
    f1[1] = *reinterpret_cast<const float4*>(gH + 68);

    // main loop: 32 K-chunks (64B each), 2 per trip, static buffer/reg roles
    for (int kb = 0; kb < 15; kb++) {
        const int k = kb * 2;
        G1R_ITER(k,     As0, As1, f1, f0, 1, 1)
        G1R_ITER(k + 1, As1, As0, f0, f1, 1, 1)
    }
    G1R_ITER(30, As0, As1, f1, f0, 1, 0)   // stage chunk 31, no more h
    G1R_ITER(31, As1, As0, f0, f1, 0, 0)   // drain

    // epilogue: quantize, frag-layout store, norm2 partials (atomicAdd:
    // 8 waves each own 64 of the row's 512 cols)
    #pragma unroll
    for (int i = 0; i < 4; i++) {
        #pragma unroll
        for (int r = 0; r < 4; r++) {
            const int row_g = blk * 64 + i * 16 + quad * 4 + r;
            float pw = 0.f;
            #pragma unroll
            for (int jp = 0; jp < 2; jp++) {
                const int pk = __builtin_amdgcn_cvt_pk_fp8_f32(
                    acc[i][2 * jp][r], acc[i][2 * jp + 1][r], 0, 0);
                Z8F[fl_off(row_g, (wave * 4 + 2 * jp) * 16 + l15)]     = (uchar)(pk & 0xff);
                Z8F[fl_off(row_g, (wave * 4 + 2 * jp + 1) * 16 + l15)] = (uchar)((pk >> 8) & 0xff);
                const float q0 = __builtin_amdgcn_cvt_f32_fp8(pk, 0);
                const float q1 = __builtin_amdgcn_cvt_f32_fp8(pk, 1);
                pw += q0 * q0 + q1 * q1;
            }
            pw += __shfl_xor(pw, 1, 16);
            pw += __shfl_xor(pw, 2, 16);
            pw += __shfl_xor(pw, 4, 16);
            pw += __shfl_xor(pw, 8, 16);
            if (l15 == 0) atomicAdd(&norm2[row_g], pw);
        }
    }
}

// ---------------------------------------------------------------- g1_slow (fallback, fp32 in)
__global__ __launch_bounds__(256) void g1_slow(
    const float* __restrict__ h, const float* __restrict__ W,
    uchar* __restrict__ Z8F, float* __restrict__ norm2)
{
    __shared__ __align__(16) unsigned short As[128][40];
    __shared__ __align__(16) unsigned short Bs[128][40];

    const int bn = blockIdx.x, bm = blockIdx.y;
    const int t = threadIdx.x;
    const int wave = t >> 6, lane = t & 63;
    const int wm = wave & 1, wn = wave >> 1;
    const int quad = lane >> 4, l15 = lane & 15;

    floatx4 acc[4][4];
    #pragma unroll
    for (int i = 0; i < 4; i++)
        #pragma unroll
        for (int j = 0; j < 4; j++) acc[i][j] = {0.f, 0.f, 0.f, 0.f};

    const int lrow = t >> 1, lhalf = t & 1;
    const float* ga = h + (size_t)(bm * 128 + lrow) * 2048 + lhalf * 16;
    const float* gb = W + (size_t)(bn * 128 + lrow) * 2048 + lhalf * 16;

    for (int k0 = 0; k0 < 2048; k0 += 32) {
        #pragma unroll
        for (int c = 0; c < 4; c++) {
            const float4 va = *reinterpret_cast<const float4*>(ga + k0 + c * 4);
            const float4 vb = *reinterpret_cast<const float4*>(gb + k0 + c * 4);
            ushort4 ua = make_ushort4(f2bf(va.x), f2bf(va.y), f2bf(va.z), f2bf(va.w));
            ushort4 ub = make_ushort4(f2bf(vb.x), f2bf(vb.y), f2bf(vb.z), f2bf(vb.w));
            *reinterpret_cast<ushort4*>(&As[lrow][lhalf * 16 + c * 4]) = ua;
            *reinterpret_cast<ushort4*>(&Bs[lrow][lhalf * 16 + c * 4]) = ub;
        }
        __syncthreads();
        bf16x8 af[4], bfr[4];
        #pragma unroll
        for (int i = 0; i < 4; i++)
            af[i] = *reinterpret_cast<const bf16x8*>(&As[wm * 64 + i * 16 + l15][quad * 8]);
        #pragma unroll
        for (int j = 0; j < 4; j++)
            bfr[j] = *reinterpret_cast<const bf16x8*>(&Bs[wn * 64 + j * 16 + l15][quad * 8]);
        #pragma unroll
        for (int i = 0; i < 4; i++)
            #pragma unroll
            for (int j = 0; j < 4; j++)
                acc[i][j] = __builtin_amdgcn_mfma_f32_16x16x32_bf16(af[i], bfr[j], acc[i][j], 0, 0, 0);
        __syncthreads();
    }

    #pragma unroll
    for (int i = 0; i < 4; i++) {
        #pragma unroll
        for (int r = 0; r < 4; r++) {
            const int row_g = bm * 128 + wm * 64 + i * 16 + quad * 4 + r;
            const int pk01 = __builtin_amdgcn_cvt_pk_fp8_f32(acc[i][0][r], acc[i][1][r], 0, 0);
            const int pk23 = __builtin_amdgcn_cvt_pk_fp8_f32(acc[i][2][r], acc[i][3][r], 0, 0);
            const uchar q8[4] = { (uchar)(pk01 & 0xff), (uchar)((pk01 >> 8) & 0xff),
                                  (uchar)(pk23 & 0xff), (uchar)((pk23 >> 8) & 0xff) };
            #pragma unroll
            for (int j = 0; j < 4; j++) {
                const int col_g = bn * 128 + wn * 64 + j * 16 + l15;
                Z8F[fl_off(row_g, col_g)] = q8[j];
            }
            const float q0 = __builtin_amdgcn_cvt_f32_fp8(pk01, 0);
            const float q1 = __builtin_amdgcn_cvt_f32_fp8(pk01, 1);
            const float q2 = __builtin_amdgcn_cvt_f32_fp8(pk23, 0);
            const float q3 = __builtin_amdgcn_cvt_f32_fp8(pk23, 1);
            float pw = q0 * q0 + q1 * q1 + q2 * q2 + q3 * q3;
            pw += __shfl_xor(pw, 1, 16);
            pw += __shfl_xor(pw, 2, 16);
            pw += __shfl_xor(pw, 4, 16);
            pw += __shfl_xor(pw, 8, 16);
            if (l15 == 0) atomicAdd(&norm2[row_g], pw);
        }
    }
}

// ---------------------------------------------------------------- g2_main
// S = Z8F[:8192g] @ Z8F[8192g:]^T, fp8 16x16x32 MFMA, 128x128 tile.
// r11: wave w owns rows [w*32,+32) x 128 cols; A global (read once/block),
// B half-K (32 KB) in LDS, restaged mid-loop. 4 blocks/CU -> 4 waves/SIMD.
__global__ __launch_bounds__(256, 4) void g2_main(
    const uchar* __restrict__ Z8F, const float* __restrict__ norm2,
    float* __restrict__ rowse, float* __restrict__ bsum, float* __restrict__ bdiag)
{
    __shared__ __align__(16) uchar Bs[32768];      // half-K B tile (32 KB)
    __shared__ float red[8];
    float (*lds_red)[20] = (float (*)[20])(void*)Bs;  // post-loop overlay [128][20]

    // XCD-aware remap: 4096 blocks, o%8 = XCD, 512 blocks/XCD.
    const int o = blockIdx.y * 64 + blockIdx.x;
    const int xcd = o & 7, idx = o >> 3;           // idx in [0,512)
    const int bg = idx >> 7, r = idx & 127;        // bn-group, inner
    const int bm = xcd * 8 + (r >> 4);             // 0..63
    const int bn = bg * 16 + (r & 15);             // 0..63
    const int t = threadIdx.x;
    const int wave = t >> 6, lane = t & 63;
    const int quad = lane >> 4, l15 = lane & 15;

    // B tile = Z rows [8192 + bn*128, +128) x K=512 B, frag layout: 8 groups
    // of 8 KB; half h = bytes [h*4096, +4096) of each group (c in [h*8,+8)).
    const uchar* gB = Z8F + (size_t)(512 + bn * 8) * 8192 + t * 16;
    #pragma unroll
    for (int s = 0; s < 8; s++)                     // stage half 0
        async_copy16(gB + s * 8192, &Bs[s * 4096 + wave * 1024]);

    floatx4 acc[2][8];
    #pragma unroll
    for (int i = 0; i < 2; i++)
        #pragma unroll
        for (int j = 0; j < 8; j++) acc[i][j] = {0.f, 0.f, 0.f, 0.f};

    // A: wave w owns row groups bm*8 + w*2 + i (i=0,1), all 16 c-steps.
    const uchar* baseA = Z8F + (size_t)(bm * 8 + wave * 2) * 8192 + lane * 8;

    // distance-2 A ring (cheap even if the scheduler re-sinks it; TLP is
    // the primary latency cover at 4 waves/SIMD)
    long ab[3][2];
    #pragma unroll
    for (int d = 0; d < 2; d++)
        #pragma unroll
        for (int i = 0; i < 2; i++)
            ab[d][i] = *reinterpret_cast<const long*>(baseA + i * 8192 + d * 512);

    __syncthreads();   // half 0 staged & visible

    #pragma unroll
    for (int c = 0; c < 16; c++) {
        const int cl = c & 7;
        if (c < 14) {
            #pragma unroll
            for (int i = 0; i < 2; i++)
                ab[(c + 2) % 3][i] = *reinterpret_cast<const long*>(
                    baseA + i * 8192 + (c + 2) * 512);
        }
        long bb[8];
        #pragma unroll
        for (int j = 0; j < 8; j++)
            bb[j] = *reinterpret_cast<const long*>(&Bs[j * 4096 + cl * 512 + lane * 8]);
        __builtin_amdgcn_s_setprio(1);
        #pragma unroll
        for (int i = 0; i < 2; i++)
            #pragma unroll
            for (int j = 0; j < 8; j++)
                acc[i][j] = __builtin_amdgcn_mfma_f32_16x16x32_fp8_fp8(
                    ab[c % 3][i], bb[j], acc[i][j], 0, 0, 0);
        __builtin_amdgcn_s_setprio(0);
        if (c == 7) {
            __syncthreads();                        // all waves done with half 0
            #pragma unroll
            for (int s = 0; s < 8; s++)             // stage half 1
                async_copy16(gB + s * 8192 + 4096, &Bs[s * 4096 + wave * 1024]);
            __syncthreads();                        // drained & visible
        }
    }

    __syncthreads();   // all waves done reading Bs before lds_red overlay

    // Slim epilogue: sim2 = dot * rz * rc * (10*log2e); rowexp via exp2.
    float rc8[8];
    #pragma unroll
    for (int j = 0; j < 8; j++)
        rc8[j] = rsqrtf(fmaxf(norm2[8192 + bn * 128 + j * 16 + l15], 1e-30f));

    const bool diagblk = (bm == bn);
    float s_tot2 = 0.f, s_diag2 = 0.f;
    #pragma unroll
    for (int i = 0; i < 2; i++) {
        #pragma unroll
        for (int rr = 0; rr < 4; rr++) {
            const int row_t = wave * 32 + i * 16 + quad * 4 + rr;
            const float rzl2 = rsqrtf(fmaxf(norm2[bm * 128 + row_t], 1e-30f)) * 14.4269504089f;
            float rx = 0.f;
            #pragma unroll
            for (int j = 0; j < 8; j++) {
                const float sim2 = acc[i][j][rr] * rzl2 * rc8[j];
                s_tot2 += sim2;
                rx += exp2f(sim2);
                if (diagblk && j == wave * 2 + i && l15 == quad * 4 + rr)
                    s_diag2 += sim2;
            }
            lds_red[row_t][l15] = rx;   // row stride 20: quads 2-way = free
        }
    }
    __syncthreads();

    // batched row reduction: 256 threads -> 128 rows x 2 col-half partials
    {
        const int row = t >> 1, half = t & 1;
        float v = 0.f;
        #pragma unroll
        for (int cc = 0; cc < 8; cc++) v += lds_red[row][half * 8 + cc];
        v += __shfl_xor(v, 1, 64);          // combine the two col-halves
        if (half == 0) atomicAdd(&rowse[bm * 128 + row], v);
    }

    #pragma unroll
    for (int off = 32; off; off >>= 1) {
        s_tot2  += __shfl_xor(s_tot2, off, 64);
        s_diag2 += __shfl_xor(s_diag2, off, 64);
    }
    if (lane == 0) { red[wave] = s_tot2; red[4 + wave] = s_diag2; }
    __syncthreads();
    if (t == 0) {
        bsum[bm * 64 + bn]  = (red[0] + red[1] + red[2] + red[3]) * 0.69314718056f;
        bdiag[bm * 64 + bn] = (red[4] + red[5] + red[6] + red[7]) * 0.69314718056f;
    }
}

// ---------------------------------------------------------------- finalize
__global__ __launch_bounds__(256) void finalize_kernel(
    const float* __restrict__ rowse, const float* __restrict__ bsum,
    const float* __restrict__ bdiag, float* __restrict__ out)
{
    float a = 0.f, b = 0.f, c = 0.f;
    for (int i = threadIdx.x; i < 8192; i += 256) a += logf(rowse[i]);
    for (int i = threadIdx.x; i < 4096; i += 256) { b += bsum[i]; c += bdiag[i]; }
    #pragma unroll
    for (int off = 32; off; off >>= 1) {
        a += __shfl_xor(a, off, 64);
        b += __shfl_xor(b, off, 64);
        c += __shfl_xor(c, off, 64);
    }
    __shared__ float ra[4], rb[4], rc[4];
    const int wave = threadIdx.x >> 6, lane = threadIdx.x & 63;
    if (lane == 0) { ra[wave] = a; rb[wave] = b; rc[wave] = c; }
    __syncthreads();
    if (threadIdx.x == 0) {
        const float A = ra[0] + ra[1] + ra[2] + ra[3];
        const float B = rb[0] + rb[1] + rb[2] + rb[3];
        const float C = rc[0] + rc[1] + rc[2] + rc[3];
        const float diag_mean = C / 8192.f;
        out[0] = A / 8192.f - diag_mean;            // loss
        out[1] = diag_mean;                         // sim_pos
        out[2] = B / (8192.f * 8192.f);             // sim_mean
    }
}

// ---------------------------------------------------------------- launch
extern "C" void kernel_launch(void* const* d_in, const int* in_sizes, int n_in,
                              void* d_out, int out_size, void* d_ws, size_t ws_size,
                              hipStream_t stream) {
    const float* h = (const float*)d_in[0];   // [16384, 2048]
    const float* W = (const float*)d_in[1];   // [512, 2048]
    float* out = (float*)d_out;               // [3]

    char* ws = (char*)d_ws;
    float* norm2 = (float*)(ws);                            // 16384 f @ 0
    float* rowse = (float*)(ws + 65536);                    //  8192 f
    float* bsum  = (float*)(ws + 98304);                    //  4096 f
    float* bdiag = (float*)(ws + 114688);                   //  4096 f
    uchar* Z8F   = (uchar*)(ws + 131072);                   // frag-layout fp8 (8.39 MB)
    uchar* W8F   = (uchar*)(ws + 8519680);                  // frag-layout W fp8 (1 MB)
    const size_t NEED_FAST = 9568256ull;                    // ~9.6 MB

    hipMemsetAsync(ws, 0, 131072, stream);    // zero norm2 + rowse (+bsum/bdiag)

    if (ws_size >= NEED_FAST) {
        hipLaunchKernelGGL(cast_w_frag, dim3(512), dim3(256), 0, stream, W, W8F);
        hipLaunchKernelGGL(g1r, dim3(256), dim3(512), 0, stream, h, W8F, Z8F, norm2);
    } else {
        hipLaunchKernelGGL(g1_slow, dim3(4, 128), dim3(256), 0, stream, h, W, Z8F, norm2);
    }
    hipLaunchKernelGGL(g2_main, dim3(64, 64), dim3(256), 0, stream, Z8F, norm2, rowse, bsum, bdiag);
    hipLaunchKernelGGL(finalize_kernel, dim3(1), dim3(256), 0, stream, rowse, bsum, bdiag, out);
}